// Round 11
// baseline (217.162 us; speedup 1.0000x reference)
//
#include <hip/hip_runtime.h>
#include <hip/hip_fp16.h>

// 2-layer GCN via CSR gather built by a two-level counting sort with
// fixed-capacity (padded) coarse buckets.
//   k_init_gcur: gcur[b] = b*CAP
//   k_partition: 4-way sub-hist (per wave-pair) -> scan w/ per-sub cursor bases
//                -> rank into LDS-sorted order -> linear coalesced emit
//   k_bucket:    1024 thr, edges staged into LDS; 4-way sub-hist + scan + place
//   k_gemm1:     g = fp16(dis * (x@W1)), 8 lanes/row
//   k_gather1:   8 lanes/node; int4 ssrc loads (peel to 16B align); 8 random
//                half2 g loads in flight; fused relu+bias+dot(W2) -> t
//   k_gather2:   8 lanes/node scalar gather (unroll x4) -> out
// R8 lesson: per-edge fp32 LDS atomics (ds_add) ~6x slower than sorted-gather.
// R9 lesson: per-thread sequential row reads are line-complete (not over-fetch).

#define CB 8                  // coarse bucket = col >> CB (256 nodes/bucket)
#define CAP 9216              // max edges per bucket (mean 8192 + 11 sigma)
#define TILE 4096             // edges per partition block (512 thr x 8)

__global__ void k_init_gcur(int* __restrict__ gcur, int nb) {
    int b = blockIdx.x * blockDim.x + threadIdx.x;
    if (b < nb) gcur[b] = b * CAP;
}

// Pack (col&255)<<17 | row  (row < 2^17).
__global__ void __launch_bounds__(512) k_partition(
        const int* __restrict__ row, const int* __restrict__ col,
        int* __restrict__ gcur, int* __restrict__ ebuf, int e, int nb) {
    __shared__ int h4[4][512];           // sub-histograms -> sub-cursors
    __shared__ int sc[512];              // scan buffer
    __shared__ int gdelta[512];          // gbase[b] - lbase[b]
    __shared__ int sval[TILE];           // tile sorted by bucket
    __shared__ unsigned short sbkt[TILE];
    const int base = blockIdx.x * TILE;
    const int cnt = min(TILE, e - base);
    const int t = threadIdx.x;
    const int sub = (t >> 6) & 3;        // wave-pair id
#pragma unroll
    for (int s = 0; s < 4; ++s) h4[s][t] = 0;
    __syncthreads();
#pragma unroll
    for (int k = 0; k < TILE / 512; ++k) {
        int i = base + (k << 9) + t;
        if (i < e) atomicAdd(&h4[sub][col[i] >> CB], 1);
    }
    __syncthreads();
    int c0 = h4[0][t], c1 = h4[1][t], c2 = h4[2][t], c3 = h4[3][t];
    int v = c0 + c1 + c2 + c3;
    sc[t] = v;
    __syncthreads();
    for (int off = 1; off < 512; off <<= 1) {
        int add = (t >= off) ? sc[t - off] : 0;
        __syncthreads();
        sc[t] += add;
        __syncthreads();
    }
    int excl = sc[t] - v;
    int gb = v ? atomicAdd(&gcur[t], v) : 0;   // t >= nb has v == 0
    gdelta[t] = gb - excl;
    // per-sub cursor bases (consistent block-local ranking)
    h4[0][t] = excl;
    h4[1][t] = excl + c0;
    h4[2][t] = excl + c0 + c1;
    h4[3][t] = excl + c0 + c1 + c2;
    __syncthreads();
#pragma unroll
    for (int k = 0; k < TILE / 512; ++k) {
        int i = base + (k << 9) + t;
        if (i < e) {
            int c = col[i], r = row[i];
            int b = c >> CB;
            int p = atomicAdd(&h4[sub][b], 1);
            sval[p] = ((c & ((1 << CB) - 1)) << 17) | r;
            sbkt[p] = (unsigned short)b;
        }
    }
    __syncthreads();
    for (int j = t; j < cnt; j += 512) {       // coalesced emit
        int b = sbkt[j];
        int p = gdelta[b] + j;                 // == gbase[b] + (j - lbase[b])
        if (p < (b + 1) * CAP) ebuf[p] = sval[j];  // overflow guard
    }
}

// One block per bucket, 1024 threads: stage edges into LDS once; 4-way
// sub-hist + scan (lanes<256) + place from LDS with per-sub cursors.
__global__ void __launch_bounds__(1024) k_bucket(
        const int* __restrict__ ebuf, const int* __restrict__ gcur,
        int* __restrict__ begA, int* __restrict__ endA, int* __restrict__ ssrc,
        float* __restrict__ dis, int n) {
    __shared__ int ev[CAP];            // 36 KB staged bucket
    __shared__ int h4[4][256];
    __shared__ int sc[256];
    const int b = blockIdx.x, t = threadIdx.x;
    const int base = b * CAP;
    const int cnt = min(gcur[b] - base, CAP);
    const int sub = (t >> 6) & 3;
    if (t < 1024) {
#pragma unroll
        for (int s = 0; s < 4; ++s) if (t < 256) h4[s][t] = 0;
    }
    __syncthreads();
    for (int j = t; j < cnt; j += 1024) {
        int v = ebuf[base + j];
        ev[j] = v;
        atomicAdd(&h4[sub][v >> 17], 1);
    }
    __syncthreads();
    int c0 = 0, c1 = 0, c2 = 0, c3 = 0, v = 0;
    if (t < 256) {
        c0 = h4[0][t]; c1 = h4[1][t]; c2 = h4[2][t]; c3 = h4[3][t];
        v = c0 + c1 + c2 + c3;
        sc[t] = v;
    }
    __syncthreads();
    for (int off = 1; off < 256; off <<= 1) {
        int add = 0;
        if (t < 256 && t >= off) add = sc[t - off];
        __syncthreads();
        if (t < 256) sc[t] += add;
        __syncthreads();
    }
    if (t < 256) {
        int excl = sc[t] - v;
        int node = (b << CB) + t;
        if (node < n) {
            begA[node] = base + excl;
            endA[node] = base + excl + v;
            dis[node] = rsqrtf((float)(v + 1));
        }
        h4[0][t] = excl;
        h4[1][t] = excl + c0;
        h4[2][t] = excl + c0 + c1;
        h4[3][t] = excl + c0 + c1 + c2;
    }
    __syncthreads();
    for (int j = t; j < cnt; j += 1024) {
        int val = ev[j];
        int p = atomicAdd(&h4[sub][val >> 17], 1);
        ssrc[base + p] = val & 0x1FFFF;
    }
}

// g[N,16] (fp16) = dis[row] * (x[N,128] @ W1[128,16]).
// 8 lanes/row: coalesced float4 reads, butterfly reduce, 32B coalesced store.
__global__ void k_gemm1(const float* __restrict__ x, const float* __restrict__ W1,
                        const float* __restrict__ dis, __half* __restrict__ gh, int n) {
    __shared__ float wt[16 * 128];
    for (int t = threadIdx.x; t < 2048; t += blockDim.x) {
        int j = t >> 7, k = t & 127;
        wt[t] = W1[k * 16 + j];
    }
    __syncthreads();
    int t = blockIdx.x * blockDim.x + threadIdx.x;
    if (t >= n * 8) return;
    int r = t >> 3, l = t & 7;
    const float4* x4 = (const float4*)x;
    const float4* w4 = (const float4*)wt;
    float4 va = x4[(size_t)r * 32 + l];
    float4 vb = x4[(size_t)r * 32 + l + 8];
    float4 vc = x4[(size_t)r * 32 + l + 16];
    float4 vd = x4[(size_t)r * 32 + l + 24];
    float acc[16];
#pragma unroll
    for (int j = 0; j < 16; ++j) {
        float4 wa = w4[j * 32 + l];
        float4 wb = w4[j * 32 + l + 8];
        float4 wc = w4[j * 32 + l + 16];
        float4 wd = w4[j * 32 + l + 24];
        acc[j] = va.x * wa.x + va.y * wa.y + va.z * wa.z + va.w * wa.w
               + vb.x * wb.x + vb.y * wb.y + vb.z * wb.z + vb.w * wb.w
               + vc.x * wc.x + vc.y * wc.y + vc.z * wc.z + vc.w * wc.w
               + vd.x * wd.x + vd.y * wd.y + vd.z * wd.z + vd.w * wd.w;
    }
#pragma unroll
    for (int j = 0; j < 16; ++j) {
#pragma unroll
        for (int m = 4; m >= 1; m >>= 1) acc[j] += __shfl_xor(acc[j], m, 8);
    }
    float d = dis[r];
    __half2 hh = __floats2half2_rn(d * acc[2 * l], d * acc[2 * l + 1]);
    ((__half2*)gh)[(size_t)r * 8 + l] = hh;  // 8 lanes -> 32B coalesced
}

// 8 threads/node; ssrc read as int4 (peel to 16B alignment); 8 random half2
// g loads in flight; fp32 accumulate; fused relu+bias+dot(W2).
__global__ void k_gather1(const int* __restrict__ begA, const int* __restrict__ endA,
                          const int* __restrict__ ssrc,
                          const __half2* __restrict__ g2, const float* __restrict__ dis,
                          const float* __restrict__ b1, const float* __restrict__ W2,
                          float* __restrict__ tbuf, int n) {
    int t = blockIdx.x * blockDim.x + threadIdx.x;
    if (t >= n * 8) return;
    int i = t >> 3, f2 = t & 7;
    float di = dis[i];
    int beg = begA[i], end = endA[i];
    float2 acc = __half22float2(g2[(size_t)i * 8 + f2]);  // self-loop
    float2 acc1 = make_float2(0.f, 0.f);
    int e = beg;
    while (e < end && (e & 3)) {                // peel to int4 alignment
        float2 v = __half22float2(g2[(size_t)ssrc[e] * 8 + f2]);
        acc.x += v.x; acc.y += v.y;
        ++e;
    }
    for (; e + 8 <= end; e += 8) {
        int4 sa = *(const int4*)&ssrc[e];
        int4 sb = *(const int4*)&ssrc[e + 4];
        float2 v0 = __half22float2(g2[(size_t)sa.x * 8 + f2]);
        float2 v1 = __half22float2(g2[(size_t)sa.y * 8 + f2]);
        float2 v2 = __half22float2(g2[(size_t)sa.z * 8 + f2]);
        float2 v3 = __half22float2(g2[(size_t)sa.w * 8 + f2]);
        float2 v4 = __half22float2(g2[(size_t)sb.x * 8 + f2]);
        float2 v5 = __half22float2(g2[(size_t)sb.y * 8 + f2]);
        float2 v6 = __half22float2(g2[(size_t)sb.z * 8 + f2]);
        float2 v7 = __half22float2(g2[(size_t)sb.w * 8 + f2]);
        acc.x  += v0.x; acc.y  += v0.y;  acc1.x += v1.x; acc1.y += v1.y;
        acc.x  += v2.x; acc.y  += v2.y;  acc1.x += v3.x; acc1.y += v3.y;
        acc.x  += v4.x; acc.y  += v4.y;  acc1.x += v5.x; acc1.y += v5.y;
        acc.x  += v6.x; acc.y  += v6.y;  acc1.x += v7.x; acc1.y += v7.y;
    }
    for (; e < end; ++e) {
        float2 v = __half22float2(g2[(size_t)ssrc[e] * 8 + f2]);
        acc.x += v.x; acc.y += v.y;
    }
    acc.x += acc1.x; acc.y += acc1.y;
    int f = f2 * 2;
    float u = fmaxf(di * acc.x + b1[f], 0.f) * W2[f]
            + fmaxf(di * acc.y + b1[f + 1], 0.f) * W2[f + 1];
#pragma unroll
    for (int m = 4; m >= 1; m >>= 1) u += __shfl_xor(u, m, 8);
    if (f2 == 0) tbuf[i] = di * u;
}

// 8 threads/node, lane-strided edges (coalesced ssrc), unroll x4 for MLP:
// out[i] = dis[i] * (sum_e t[src] + t[i]) + b2
__global__ void k_gather2(const int* __restrict__ begA, const int* __restrict__ endA,
                          const int* __restrict__ ssrc,
                          const float* __restrict__ tbuf, const float* __restrict__ dis,
                          const float* __restrict__ b2, float* __restrict__ out, int n) {
    int t = blockIdx.x * blockDim.x + threadIdx.x;
    if (t >= n * 8) return;
    int i = t >> 3, l = t & 7;
    int beg = begA[i], end = endA[i];
    float acc = (l == 0) ? tbuf[i] : 0.f;
    float acc1 = 0.f;
    int e = beg + l;
    for (; e + 24 < end; e += 32) {
        int s0 = ssrc[e], s1 = ssrc[e + 8], s2 = ssrc[e + 16], s3 = ssrc[e + 24];
        float v0 = tbuf[s0], v1 = tbuf[s1], v2 = tbuf[s2], v3 = tbuf[s3];
        acc += v0; acc1 += v1; acc += v2; acc1 += v3;
    }
    for (; e < end; e += 8) acc += tbuf[ssrc[e]];
    acc += acc1;
#pragma unroll
    for (int m = 4; m >= 1; m >>= 1) acc += __shfl_xor(acc, m, 8);
    if (l == 0) out[i] = dis[i] * acc + b2[0];
}

extern "C" void kernel_launch(void* const* d_in, const int* in_sizes, int n_in,
                              void* d_out, int out_size, void* d_ws, size_t ws_size,
                              hipStream_t stream) {
    const float* x  = (const float*)d_in[0];
    const int*   ei = (const int*)d_in[1];
    const float* W1 = (const float*)d_in[2];
    const float* b1 = (const float*)d_in[3];
    const float* W2 = (const float*)d_in[4];
    const float* b2 = (const float*)d_in[5];
    float* out = (float*)d_out;

    const int N = in_sizes[0] / 128;   // 100000
    const int E = in_sizes[1] / 2;     // 3200000
    const int* row = ei;        // edge_index[0] = source
    const int* col = ei + E;    // edge_index[1] = target
    const int NB = (N + 255) >> CB;    // coarse buckets (391)
    const size_t PADE = (size_t)NB * CAP;  // padded edge capacity

    // workspace (4B units): ebuf[PADE] (aliased by gh fp16 after k_bucket) |
    // ssrc[PADE] | dis[N] | tbuf[N] | begA[N] | endA[N] | gcur[512]
    size_t bigsz = PADE > (size_t)N * 8 ? PADE : (size_t)N * 8;
    int*    ebuf = (int*)d_ws;
    __half* gh   = (__half*)d_ws;      // aliases ebuf (dead before k_gemm1)
    int*    ssrc = (int*)d_ws + bigsz;
    float*  dis  = (float*)(ssrc + PADE);
    float*  tbuf = dis + N;
    int*    begA = (int*)(tbuf + N);
    int*    endA = begA + N;
    int*    gcur = endA + N;

    auto cdiv = [](int a, int b) { return (a + b - 1) / b; };

    k_init_gcur<<<cdiv(NB, 256),    256,  0, stream>>>(gcur, NB);
    k_partition<<<cdiv(E, TILE),    512,  0, stream>>>(row, col, gcur, ebuf, E, NB);
    k_bucket   <<<NB,               1024, 0, stream>>>(ebuf, gcur, begA, endA, ssrc, dis, N);
    k_gemm1    <<<cdiv(N * 8, 256), 256,  0, stream>>>(x, W1, dis, gh, N);
    k_gather1  <<<cdiv(N * 8, 256), 256,  0, stream>>>(begA, endA, ssrc, (const __half2*)gh,
                                                       dis, b1, W2, tbuf, N);
    k_gather2  <<<cdiv(N * 8, 256), 256,  0, stream>>>(begA, endA, ssrc, tbuf, dis, b2, out, N);
}

// Round 12
// 214.510 us; speedup vs baseline: 1.0124x; 1.0124x over previous
//
#include <hip/hip_runtime.h>
#include <hip/hip_fp16.h>

// 2-layer GCN via bucket counting sort with layer-1 aggregation fused into the
// fine-sort kernel:
//   k_init_gcur: gcur[b] = b*CAP
//   k_partition: LDS coarse hist -> scan -> rank into LDS order -> coalesced emit
//   k_deg:       per-bucket 4-way LDS hist of ebuf -> dis = rsqrt(deg+1)
//   k_gemm1:     g = fp16(dis * (x@W1)), 8 lanes/row
//   k_fused1:    per bucket: stage ebuf in LDS, hist+scan+place -> srt[] (LDS) +
//                ssrc/beg/end (global, for layer 2); then 4 lanes/node aggregate
//                random g rows (8 loads in flight) + relu+bias+dot(W2) -> tbuf
//   k_gather2:   8 lanes/node scalar gather (unroll x4) -> out
// R8 lesson: per-edge fp32 LDS atomics ~6x slower than sorted-gather.
// R9 lesson: per-thread sequential row reads are line-complete.
// R11 lesson: 4-way sub-hist in partition costs occupancy (36KB LDS) for no gain.

#define CB 8                  // coarse bucket = col >> CB (256 nodes/bucket)
#define CAP 9216              // max edges per bucket (mean 8192 + 11 sigma)
#define TILE 4096             // edges per partition block (512 thr x 8)

__global__ void k_init_gcur(int* __restrict__ gcur, int nb) {
    int b = blockIdx.x * blockDim.x + threadIdx.x;
    if (b < nb) gcur[b] = b * CAP;
}

// Pack (col&255)<<17 | row  (row < 2^17).  (R10 form: 30KB LDS, 5 blocks/CU)
__global__ void __launch_bounds__(512) k_partition(
        const int* __restrict__ row, const int* __restrict__ col,
        int* __restrict__ gcur, int* __restrict__ ebuf, int e, int nb) {
    __shared__ int hist[512];            // counts -> local cursor
    __shared__ int lbase[512];           // scan buffer
    __shared__ int gdelta[512];          // gbase[b] - lbase[b]
    __shared__ int sval[TILE];           // tile sorted by bucket
    __shared__ unsigned short sbkt[TILE];
    const int base = blockIdx.x * TILE;
    const int cnt = min(TILE, e - base);
    const int t = threadIdx.x;
    hist[t] = 0;
    __syncthreads();
#pragma unroll
    for (int k = 0; k < TILE / 512; ++k) {
        int i = base + (k << 9) + t;
        if (i < e) atomicAdd(&hist[col[i] >> CB], 1);
    }
    __syncthreads();
    int v = hist[t];
    lbase[t] = v;
    __syncthreads();
    for (int off = 1; off < 512; off <<= 1) {
        int add = (t >= off) ? lbase[t - off] : 0;
        __syncthreads();
        lbase[t] += add;
        __syncthreads();
    }
    int excl = lbase[t] - v;
    int gb = v ? atomicAdd(&gcur[t], v) : 0;   // t >= nb has v == 0
    gdelta[t] = gb - excl;
    hist[t] = excl;                            // local rank cursor
    __syncthreads();
#pragma unroll
    for (int k = 0; k < TILE / 512; ++k) {
        int i = base + (k << 9) + t;
        if (i < e) {
            int c = col[i], r = row[i];
            int b = c >> CB;
            int p = atomicAdd(&hist[b], 1);
            sval[p] = ((c & ((1 << CB) - 1)) << 17) | r;
            sbkt[p] = (unsigned short)b;
        }
    }
    __syncthreads();
    for (int j = t; j < cnt; j += 512) {       // coalesced emit
        int b = sbkt[j];
        int p = gdelta[b] + j;                 // == gbase[b] + (j - lbase[b])
        if (p < (b + 1) * CAP) ebuf[p] = sval[j];  // overflow guard
    }
}

// Per-bucket degree -> dis (needed by gemm1 before fused aggregation).
__global__ void __launch_bounds__(256) k_deg(
        const int* __restrict__ ebuf, const int* __restrict__ gcur,
        float* __restrict__ dis, int n) {
    __shared__ int h4[4][256];
    const int b = blockIdx.x, t = threadIdx.x;
    const int base = b * CAP;
    const int cnt = min(gcur[b] - base, CAP);
    const int sub = (t >> 6) & 3;
#pragma unroll
    for (int s = 0; s < 4; ++s) h4[s][t] = 0;
    __syncthreads();
    for (int j = t; j < cnt; j += 256) atomicAdd(&h4[sub][ebuf[base + j] >> 17], 1);
    __syncthreads();
    int node = (b << CB) + t;
    if (node < n) {
        int v = h4[0][t] + h4[1][t] + h4[2][t] + h4[3][t];
        dis[node] = rsqrtf((float)(v + 1));
    }
}

// g[N,16] (fp16) = dis[row] * (x[N,128] @ W1[128,16]).
// 8 lanes/row: coalesced float4 reads, butterfly reduce, 32B coalesced store.
__global__ void k_gemm1(const float* __restrict__ x, const float* __restrict__ W1,
                        const float* __restrict__ dis, __half* __restrict__ gh, int n) {
    __shared__ float wt[16 * 128];
    for (int t = threadIdx.x; t < 2048; t += blockDim.x) {
        int j = t >> 7, k = t & 127;
        wt[t] = W1[k * 16 + j];
    }
    __syncthreads();
    int t = blockIdx.x * blockDim.x + threadIdx.x;
    if (t >= n * 8) return;
    int r = t >> 3, l = t & 7;
    const float4* x4 = (const float4*)x;
    const float4* w4 = (const float4*)wt;
    float4 va = x4[(size_t)r * 32 + l];
    float4 vb = x4[(size_t)r * 32 + l + 8];
    float4 vc = x4[(size_t)r * 32 + l + 16];
    float4 vd = x4[(size_t)r * 32 + l + 24];
    float acc[16];
#pragma unroll
    for (int j = 0; j < 16; ++j) {
        float4 wa = w4[j * 32 + l];
        float4 wb = w4[j * 32 + l + 8];
        float4 wc = w4[j * 32 + l + 16];
        float4 wd = w4[j * 32 + l + 24];
        acc[j] = va.x * wa.x + va.y * wa.y + va.z * wa.z + va.w * wa.w
               + vb.x * wb.x + vb.y * wb.y + vb.z * wb.z + vb.w * wb.w
               + vc.x * wc.x + vc.y * wc.y + vc.z * wc.z + vc.w * wc.w
               + vd.x * wd.x + vd.y * wd.y + vd.z * wd.z + vd.w * wd.w;
    }
#pragma unroll
    for (int j = 0; j < 16; ++j) {
#pragma unroll
        for (int m = 4; m >= 1; m >>= 1) acc[j] += __shfl_xor(acc[j], m, 8);
    }
    float d = dis[r];
    __half2 hh = __floats2half2_rn(d * acc[2 * l], d * acc[2 * l + 1]);
    ((__half2*)gh)[(size_t)r * 8 + l] = hh;  // 8 lanes -> 32B coalesced
}

// One block per bucket, 1024 threads, ~79KB LDS (2 blocks/CU = 32 waves):
// sort into LDS srt[] (+ global ssrc/beg/end for layer 2), then aggregate.
__global__ void __launch_bounds__(1024) k_fused1(
        const int* __restrict__ ebuf, const int* __restrict__ gcur,
        const __half2* __restrict__ g2, const float* __restrict__ b1,
        const float* __restrict__ W2, int* __restrict__ begA,
        int* __restrict__ endA, int* __restrict__ ssrc,
        float* __restrict__ tbuf, int n) {
    __shared__ int ev[CAP];            // staged bucket (unsorted)
    __shared__ int srt[CAP];           // sorted src list
    __shared__ int hist[256];          // counts -> cursors
    __shared__ int sc[256];            // scan
    __shared__ int begL[256];
    __shared__ int cntL[256];
    __shared__ float sdis[256];
    __shared__ float sB[16], sW[16];
    const int b = blockIdx.x, t = threadIdx.x;
    const int base = b * CAP;
    const int cnt = min(gcur[b] - base, CAP);
    if (t < 256) hist[t] = 0;
    if (t >= 256 && t < 272) { sB[t - 256] = b1[t - 256]; sW[t - 256] = W2[t - 256]; }
    __syncthreads();
    for (int j = t; j < cnt; j += 1024) {
        int v = ebuf[base + j];
        ev[j] = v;
        atomicAdd(&hist[v >> 17], 1);
    }
    __syncthreads();
    int v = 0;
    if (t < 256) { v = hist[t]; sc[t] = v; }
    __syncthreads();
    for (int off = 1; off < 256; off <<= 1) {
        int add = 0;
        if (t < 256 && t >= off) add = sc[t - off];
        __syncthreads();
        if (t < 256) sc[t] += add;
        __syncthreads();
    }
    if (t < 256) {
        int excl = sc[t] - v;
        begL[t] = excl;
        cntL[t] = v;
        sdis[t] = rsqrtf((float)(v + 1));
        int node = (b << CB) + t;
        if (node < n) {
            begA[node] = base + excl;
            endA[node] = base + excl + v;
        }
        hist[t] = excl;  // cursor
    }
    __syncthreads();
    for (int j = t; j < cnt; j += 1024) {
        int val = ev[j];
        int p = atomicAdd(&hist[val >> 17], 1);
        int s = val & 0x1FFFF;
        srt[p] = s;
        ssrc[base + p] = s;      // layer 2 still needs the global CSR
    }
    __syncthreads();
    // aggregation: 4 lanes/node; lane l covers features 4l..4l+3 (2 half2)
    int node = t >> 2, l = t & 3;
    int gnode = (b << CB) + node;
    if (gnode >= n) return;
    float di = sdis[node];
    int beg = begL[node], end = beg + cntL[node];
    int k0 = l * 2, k1 = l * 2 + 1;
    float2 acc0 = __half22float2(g2[(size_t)gnode * 8 + k0]);  // self-loop
    float2 acc1 = __half22float2(g2[(size_t)gnode * 8 + k1]);
    float2 bcc0 = make_float2(0.f, 0.f), bcc1 = make_float2(0.f, 0.f);
    int e = beg;
    for (; e + 4 <= end; e += 4) {        // 8 random half2 loads in flight
        int s0 = srt[e], s1 = srt[e + 1], s2 = srt[e + 2], s3 = srt[e + 3];
        float2 a0 = __half22float2(g2[(size_t)s0 * 8 + k0]);
        float2 a1 = __half22float2(g2[(size_t)s0 * 8 + k1]);
        float2 b0 = __half22float2(g2[(size_t)s1 * 8 + k0]);
        float2 b1v = __half22float2(g2[(size_t)s1 * 8 + k1]);
        float2 c0 = __half22float2(g2[(size_t)s2 * 8 + k0]);
        float2 c1 = __half22float2(g2[(size_t)s2 * 8 + k1]);
        float2 d0 = __half22float2(g2[(size_t)s3 * 8 + k0]);
        float2 d1 = __half22float2(g2[(size_t)s3 * 8 + k1]);
        acc0.x += a0.x; acc0.y += a0.y; acc1.x += a1.x; acc1.y += a1.y;
        bcc0.x += b0.x; bcc0.y += b0.y; bcc1.x += b1v.x; bcc1.y += b1v.y;
        acc0.x += c0.x; acc0.y += c0.y; acc1.x += c1.x; acc1.y += c1.y;
        bcc0.x += d0.x; bcc0.y += d0.y; bcc1.x += d1.x; bcc1.y += d1.y;
    }
    for (; e < end; ++e) {
        int s = srt[e];
        float2 a0 = __half22float2(g2[(size_t)s * 8 + k0]);
        float2 a1 = __half22float2(g2[(size_t)s * 8 + k1]);
        acc0.x += a0.x; acc0.y += a0.y; acc1.x += a1.x; acc1.y += a1.y;
    }
    acc0.x += bcc0.x; acc0.y += bcc0.y; acc1.x += bcc1.x; acc1.y += bcc1.y;
    int f = l * 4;
    float u = fmaxf(di * acc0.x + sB[f], 0.f) * sW[f]
            + fmaxf(di * acc0.y + sB[f + 1], 0.f) * sW[f + 1]
            + fmaxf(di * acc1.x + sB[f + 2], 0.f) * sW[f + 2]
            + fmaxf(di * acc1.y + sB[f + 3], 0.f) * sW[f + 3];
    u += __shfl_xor(u, 1, 4);
    u += __shfl_xor(u, 2, 4);
    if (l == 0) tbuf[gnode] = di * u;
}

// 8 threads/node, lane-strided edges (coalesced ssrc), unroll x4 for MLP:
// out[i] = dis[i] * (sum_e t[src] + t[i]) + b2
__global__ void k_gather2(const int* __restrict__ begA, const int* __restrict__ endA,
                          const int* __restrict__ ssrc,
                          const float* __restrict__ tbuf, const float* __restrict__ dis,
                          const float* __restrict__ b2, float* __restrict__ out, int n) {
    int t = blockIdx.x * blockDim.x + threadIdx.x;
    if (t >= n * 8) return;
    int i = t >> 3, l = t & 7;
    int beg = begA[i], end = endA[i];
    float acc = (l == 0) ? tbuf[i] : 0.f;
    float acc1 = 0.f;
    int e = beg + l;
    for (; e + 24 < end; e += 32) {
        int s0 = ssrc[e], s1 = ssrc[e + 8], s2 = ssrc[e + 16], s3 = ssrc[e + 24];
        float v0 = tbuf[s0], v1 = tbuf[s1], v2 = tbuf[s2], v3 = tbuf[s3];
        acc += v0; acc1 += v1; acc += v2; acc1 += v3;
    }
    for (; e < end; e += 8) acc += tbuf[ssrc[e]];
    acc += acc1;
#pragma unroll
    for (int m = 4; m >= 1; m >>= 1) acc += __shfl_xor(acc, m, 8);
    if (l == 0) out[i] = dis[i] * acc + b2[0];
}

extern "C" void kernel_launch(void* const* d_in, const int* in_sizes, int n_in,
                              void* d_out, int out_size, void* d_ws, size_t ws_size,
                              hipStream_t stream) {
    const float* x  = (const float*)d_in[0];
    const int*   ei = (const int*)d_in[1];
    const float* W1 = (const float*)d_in[2];
    const float* b1 = (const float*)d_in[3];
    const float* W2 = (const float*)d_in[4];
    const float* b2 = (const float*)d_in[5];
    float* out = (float*)d_out;

    const int N = in_sizes[0] / 128;   // 100000
    const int E = in_sizes[1] / 2;     // 3200000
    const int* row = ei;        // edge_index[0] = source
    const int* col = ei + E;    // edge_index[1] = target
    const int NB = (N + 255) >> CB;    // coarse buckets (391)
    const size_t PADE = (size_t)NB * CAP;  // padded edge capacity

    // workspace (4B units): ebuf[PADE] | gh[8N] (NO aliasing: both live in fused1)
    // | ssrc[PADE] | dis[N] | tbuf[N] | begA[N] | endA[N] | gcur[512]
    int*    ebuf = (int*)d_ws;
    __half* gh   = (__half*)((int*)d_ws + PADE);
    int*    ssrc = (int*)d_ws + PADE + (size_t)N * 8;
    float*  dis  = (float*)(ssrc + PADE);
    float*  tbuf = dis + N;
    int*    begA = (int*)(tbuf + N);
    int*    endA = begA + N;
    int*    gcur = endA + N;

    auto cdiv = [](int a, int b) { return (a + b - 1) / b; };

    k_init_gcur<<<cdiv(NB, 256),    256,  0, stream>>>(gcur, NB);
    k_partition<<<cdiv(E, TILE),    512,  0, stream>>>(row, col, gcur, ebuf, E, NB);
    k_deg      <<<NB,               256,  0, stream>>>(ebuf, gcur, dis, N);
    k_gemm1    <<<cdiv(N * 8, 256), 256,  0, stream>>>(x, W1, dis, gh, N);
    k_fused1   <<<NB,               1024, 0, stream>>>(ebuf, gcur, (const __half2*)gh,
                                                       b1, W2, begA, endA, ssrc, tbuf, N);
    k_gather2  <<<cdiv(N * 8, 256), 256,  0, stream>>>(begA, endA, ssrc, tbuf, dis, b2, out, N);
}

// Round 14
// 211.021 us; speedup vs baseline: 1.0291x; 1.0165x over previous
//
#include <hip/hip_runtime.h>
#include <hip/hip_fp16.h>

// 2-layer GCN via CSR gather built by a two-level counting sort with
// fixed-capacity (padded) coarse buckets (R10 structure, best-known config):
//   (memset)     gcur = 0; partition folds the b*CAP base into its reservation
//   k_partition: LDS coarse hist -> scan -> rank tile into LDS-sorted order ->
//                linear coalesced emit (no per-element atomics on the emit)
//   k_bucket:    1024 thr, edges staged once into LDS ev[]; fine hist+scan+place
//                -> ssrc/beg/end/dis (single global read of ebuf)
//   k_gemm1:     g = fp16(dis * (x@W1)), 8 lanes/row
//   k_gather1:   8 lanes/node half2 gather (unroll x8 for MLP) + relu + dot(W2) -> t
//   k_gather2:   8 lanes/node scalar gather (unroll x4) -> out
// R8  lesson: per-edge fp32 LDS atomics ~6x slower than sorted-gather.
// R9  lesson: per-thread sequential row reads are line-complete.
// R11 lesson: 4-way sub-hist in partition costs occupancy for no gain.
// R13 lesson: cooperative launch fails silently under graph capture — forbidden.

#define CB 8                  // coarse bucket = col >> CB (256 nodes/bucket)
#define CAP 9216              // max edges per bucket (mean 8192 + 11 sigma)
#define TILE 4096             // edges per partition block (512 thr x 8)

// Pack (col&255)<<17 | row  (row < 2^17).  gcur[] pre-zeroed; base b*CAP folded in.
__global__ void __launch_bounds__(512) k_partition(
        const int* __restrict__ row, const int* __restrict__ col,
        int* __restrict__ gcur, int* __restrict__ ebuf, int e, int nb) {
    __shared__ int hist[512];            // counts -> local cursor
    __shared__ int lbase[512];           // scan buffer
    __shared__ int gdelta[512];          // gbase[b] - lbase[b]
    __shared__ int sval[TILE];           // tile sorted by bucket
    __shared__ unsigned short sbkt[TILE];
    const int base = blockIdx.x * TILE;
    const int cnt = min(TILE, e - base);
    const int t = threadIdx.x;
    hist[t] = 0;
    __syncthreads();
#pragma unroll
    for (int k = 0; k < TILE / 512; ++k) {
        int i = base + (k << 9) + t;
        if (i < e) atomicAdd(&hist[col[i] >> CB], 1);
    }
    __syncthreads();
    int v = hist[t];
    lbase[t] = v;
    __syncthreads();
    for (int off = 1; off < 512; off <<= 1) {
        int add = (t >= off) ? lbase[t - off] : 0;
        __syncthreads();
        lbase[t] += add;
        __syncthreads();
    }
    int excl = lbase[t] - v;
    int gb = v ? (t * CAP + atomicAdd(&gcur[t], v)) : 0;  // t >= nb has v == 0
    gdelta[t] = gb - excl;
    hist[t] = excl;                            // local rank cursor
    __syncthreads();
#pragma unroll
    for (int k = 0; k < TILE / 512; ++k) {
        int i = base + (k << 9) + t;
        if (i < e) {
            int c = col[i], r = row[i];
            int b = c >> CB;
            int p = atomicAdd(&hist[b], 1);
            sval[p] = ((c & ((1 << CB) - 1)) << 17) | r;
            sbkt[p] = (unsigned short)b;
        }
    }
    __syncthreads();
    for (int j = t; j < cnt; j += 512) {       // coalesced emit
        int b = sbkt[j];
        int p = gdelta[b] + j;                 // == gbase[b] + (j - lbase[b])
        if (p < (b + 1) * CAP) ebuf[p] = sval[j];  // overflow guard
    }
}

// One block per bucket, 1024 threads: stage edges into LDS once, fine hist +
// scan (lanes<256, uniform barriers) + place from LDS.
__global__ void __launch_bounds__(1024) k_bucket(
        const int* __restrict__ ebuf, const int* __restrict__ gcur,
        int* __restrict__ begA, int* __restrict__ endA, int* __restrict__ ssrc,
        float* __restrict__ dis, int n) {
    __shared__ int ev[CAP];            // 36 KB staged bucket
    __shared__ int hist[256];
    __shared__ int sc[256];
    const int b = blockIdx.x, t = threadIdx.x;
    const int base = b * CAP;
    const int cnt = min(gcur[b], CAP);
    if (t < 256) hist[t] = 0;
    __syncthreads();
    for (int j = t; j < cnt; j += 1024) {
        int v = ebuf[base + j];
        ev[j] = v;
        atomicAdd(&hist[v >> 17], 1);
    }
    __syncthreads();
    int v = 0;
    if (t < 256) { v = hist[t]; sc[t] = v; }
    __syncthreads();
    for (int off = 1; off < 256; off <<= 1) {
        int add = 0;
        if (t < 256 && t >= off) add = sc[t - off];
        __syncthreads();
        if (t < 256) sc[t] += add;
        __syncthreads();
    }
    if (t < 256) {
        int excl = sc[t] - v;
        int node = (b << CB) + t;
        if (node < n) {
            begA[node] = base + excl;
            endA[node] = base + excl + v;
            dis[node] = rsqrtf((float)(v + 1));
        }
        hist[t] = excl;  // local cursor
    }
    __syncthreads();
    for (int j = t; j < cnt; j += 1024) {
        int val = ev[j];
        int p = atomicAdd(&hist[val >> 17], 1);
        ssrc[base + p] = val & 0x1FFFF;
    }
}

// g[N,16] (fp16) = dis[row] * (x[N,128] @ W1[128,16]).
// 8 lanes/row: coalesced float4 reads, butterfly reduce, 32B coalesced store.
__global__ void k_gemm1(const float* __restrict__ x, const float* __restrict__ W1,
                        const float* __restrict__ dis, __half* __restrict__ gh, int n) {
    __shared__ float wt[16 * 128];
    for (int t = threadIdx.x; t < 2048; t += blockDim.x) {
        int j = t >> 7, k = t & 127;
        wt[t] = W1[k * 16 + j];
    }
    __syncthreads();
    int t = blockIdx.x * blockDim.x + threadIdx.x;
    if (t >= n * 8) return;
    int r = t >> 3, l = t & 7;
    const float4* x4 = (const float4*)x;
    const float4* w4 = (const float4*)wt;
    float4 va = x4[(size_t)r * 32 + l];
    float4 vb = x4[(size_t)r * 32 + l + 8];
    float4 vc = x4[(size_t)r * 32 + l + 16];
    float4 vd = x4[(size_t)r * 32 + l + 24];
    float acc[16];
#pragma unroll
    for (int j = 0; j < 16; ++j) {
        float4 wa = w4[j * 32 + l];
        float4 wb = w4[j * 32 + l + 8];
        float4 wc = w4[j * 32 + l + 16];
        float4 wd = w4[j * 32 + l + 24];
        acc[j] = va.x * wa.x + va.y * wa.y + va.z * wa.z + va.w * wa.w
               + vb.x * wb.x + vb.y * wb.y + vb.z * wb.z + vb.w * wb.w
               + vc.x * wc.x + vc.y * wc.y + vc.z * wc.z + vc.w * wc.w
               + vd.x * wd.x + vd.y * wd.y + vd.z * wd.z + vd.w * wd.w;
    }
#pragma unroll
    for (int j = 0; j < 16; ++j) {
#pragma unroll
        for (int m = 4; m >= 1; m >>= 1) acc[j] += __shfl_xor(acc[j], m, 8);
    }
    float d = dis[r];
    __half2 hh = __floats2half2_rn(d * acc[2 * l], d * acc[2 * l + 1]);
    ((__half2*)gh)[(size_t)r * 8 + l] = hh;  // 8 lanes -> 32B coalesced
}

// 8 threads/node, half2 reads (32B/edge, L2-resident table); fp32 accumulate;
// edge loop unrolled x8 so 8 random loads are in flight per thread.
__global__ void k_gather1(const int* __restrict__ begA, const int* __restrict__ endA,
                          const int* __restrict__ ssrc,
                          const __half2* __restrict__ g2, const float* __restrict__ dis,
                          const float* __restrict__ b1, const float* __restrict__ W2,
                          float* __restrict__ tbuf, int n) {
    int t = blockIdx.x * blockDim.x + threadIdx.x;
    if (t >= n * 8) return;
    int i = t >> 3, f2 = t & 7;
    float di = dis[i];
    int beg = begA[i], end = endA[i];
    float2 acc = __half22float2(g2[(size_t)i * 8 + f2]);  // self-loop
    float2 acc1 = make_float2(0.f, 0.f);
    int e = beg;
    for (; e + 8 <= end; e += 8) {
        int s0 = ssrc[e + 0], s1 = ssrc[e + 1], s2 = ssrc[e + 2], s3 = ssrc[e + 3];
        int s4 = ssrc[e + 4], s5 = ssrc[e + 5], s6 = ssrc[e + 6], s7 = ssrc[e + 7];
        float2 v0 = __half22float2(g2[(size_t)s0 * 8 + f2]);
        float2 v1 = __half22float2(g2[(size_t)s1 * 8 + f2]);
        float2 v2 = __half22float2(g2[(size_t)s2 * 8 + f2]);
        float2 v3 = __half22float2(g2[(size_t)s3 * 8 + f2]);
        float2 v4 = __half22float2(g2[(size_t)s4 * 8 + f2]);
        float2 v5 = __half22float2(g2[(size_t)s5 * 8 + f2]);
        float2 v6 = __half22float2(g2[(size_t)s6 * 8 + f2]);
        float2 v7 = __half22float2(g2[(size_t)s7 * 8 + f2]);
        acc.x  += v0.x; acc.y  += v0.y;  acc1.x += v1.x; acc1.y += v1.y;
        acc.x  += v2.x; acc.y  += v2.y;  acc1.x += v3.x; acc1.y += v3.y;
        acc.x  += v4.x; acc.y  += v4.y;  acc1.x += v5.x; acc1.y += v5.y;
        acc.x  += v6.x; acc.y  += v6.y;  acc1.x += v7.x; acc1.y += v7.y;
    }
    for (; e < end; ++e) {
        float2 v = __half22float2(g2[(size_t)ssrc[e] * 8 + f2]);
        acc.x += v.x; acc.y += v.y;
    }
    acc.x += acc1.x; acc.y += acc1.y;
    int f = f2 * 2;
    float u = fmaxf(di * acc.x + b1[f], 0.f) * W2[f]
            + fmaxf(di * acc.y + b1[f + 1], 0.f) * W2[f + 1];
#pragma unroll
    for (int m = 4; m >= 1; m >>= 1) u += __shfl_xor(u, m, 8);
    if (f2 == 0) tbuf[i] = di * u;
}

// 8 threads/node, lane-strided edges (coalesced ssrc), unroll x4 for MLP:
// out[i] = dis[i] * (sum_e t[src] + t[i]) + b2
__global__ void k_gather2(const int* __restrict__ begA, const int* __restrict__ endA,
                          const int* __restrict__ ssrc,
                          const float* __restrict__ tbuf, const float* __restrict__ dis,
                          const float* __restrict__ b2, float* __restrict__ out, int n) {
    int t = blockIdx.x * blockDim.x + threadIdx.x;
    if (t >= n * 8) return;
    int i = t >> 3, l = t & 7;
    int beg = begA[i], end = endA[i];
    float acc = (l == 0) ? tbuf[i] : 0.f;
    float acc1 = 0.f;
    int e = beg + l;
    for (; e + 24 < end; e += 32) {
        int s0 = ssrc[e], s1 = ssrc[e + 8], s2 = ssrc[e + 16], s3 = ssrc[e + 24];
        float v0 = tbuf[s0], v1 = tbuf[s1], v2 = tbuf[s2], v3 = tbuf[s3];
        acc += v0; acc1 += v1; acc += v2; acc1 += v3;
    }
    for (; e < end; e += 8) acc += tbuf[ssrc[e]];
    acc += acc1;
#pragma unroll
    for (int m = 4; m >= 1; m >>= 1) acc += __shfl_xor(acc, m, 8);
    if (l == 0) out[i] = dis[i] * acc + b2[0];
}

extern "C" void kernel_launch(void* const* d_in, const int* in_sizes, int n_in,
                              void* d_out, int out_size, void* d_ws, size_t ws_size,
                              hipStream_t stream) {
    const float* x  = (const float*)d_in[0];
    const int*   ei = (const int*)d_in[1];
    const float* W1 = (const float*)d_in[2];
    const float* b1 = (const float*)d_in[3];
    const float* W2 = (const float*)d_in[4];
    const float* b2 = (const float*)d_in[5];
    float* out = (float*)d_out;

    const int N = in_sizes[0] / 128;   // 100000
    const int E = in_sizes[1] / 2;     // 3200000
    const int* row = ei;        // edge_index[0] = source
    const int* col = ei + E;    // edge_index[1] = target
    const int NB = (N + 255) >> CB;    // coarse buckets (391)
    const size_t PADE = (size_t)NB * CAP;  // padded edge capacity

    // workspace (4B units): ebuf[PADE] (aliased by gh fp16 after k_bucket) |
    // ssrc[PADE] | dis[N] | tbuf[N] | begA[N] | endA[N] | gcur[512]
    size_t bigsz = PADE > (size_t)N * 8 ? PADE : (size_t)N * 8;
    int*    ebuf = (int*)d_ws;
    __half* gh   = (__half*)d_ws;      // aliases ebuf (dead before k_gemm1)
    int*    ssrc = (int*)d_ws + bigsz;
    float*  dis  = (float*)(ssrc + PADE);
    float*  tbuf = dis + N;
    int*    begA = (int*)(tbuf + N);
    int*    endA = begA + N;
    int*    gcur = endA + N;

    auto cdiv = [](int a, int b) { return (a + b - 1) / b; };

    hipMemsetAsync(gcur, 0, 512 * sizeof(int), stream);
    k_partition<<<cdiv(E, TILE),    512,  0, stream>>>(row, col, gcur, ebuf, E, NB);
    k_bucket   <<<NB,               1024, 0, stream>>>(ebuf, gcur, begA, endA, ssrc, dis, N);
    k_gemm1    <<<cdiv(N * 8, 256), 256,  0, stream>>>(x, W1, dis, gh, N);
    k_gather1  <<<cdiv(N * 8, 256), 256,  0, stream>>>(begA, endA, ssrc, (const __half2*)gh,
                                                       dis, b1, W2, tbuf, N);
    k_gather2  <<<cdiv(N * 8, 256), 256,  0, stream>>>(begA, endA, ssrc, tbuf, dis, b2, out, N);
}